// Round 1
// baseline (115.191 us; speedup 1.0000x reference)
//
#include <hip/hip_runtime.h>
#include <math.h>

#define B_  8
#define S_  2048
#define H_  256
#define HK_ 128
#define P_  64
#define NQ_ 20
#define M_  (B_*S_)          // 16384 rows
// per-batch accumulator: G[20][64]@0, E[20][64]@1280, T[64]@2560, W[20]@2624, n[20]@2644, pad->2688
#define ACC_STRIDE 2688
#define NREP 4               // replicated global accumulators: spreads atomic contention 4x

// ws layout (float units)
#define WS_CONF  0
#define WS_ACC   16384                            // NREP*8*2688 = 86016 floats
#define WS_WT    (16384 + NREP*B_*ACC_STRIDE)     // 102400; bf16 frags: 65536 shorts

typedef __attribute__((ext_vector_type(8))) short bf16x8;
typedef __attribute__((ext_vector_type(4))) float f32x4;

// ---------------------------------------------------------------------------
// Kernel 0: prep — round w1 (fp32 [k=256][n=128]) RNE to bf16 and scatter into
// MFMA B-fragment order wtf[mlp][kt(8)][nt(8)][lane(64)][j(8)]:
//   lane l -> col=l&15, quad=l>>4;  element j: B[k = kt*32+quad*8+j][n = nt*16+col]
// Also zeros the NREP replicated ws accumulator regions.
// ---------------------------------------------------------------------------
__global__ void prep_kernel(const float* __restrict__ sw1, const float* __restrict__ cw1,
                            short* __restrict__ wtf, float* __restrict__ ws_acc)
{
    const int t = blockIdx.x * 256 + threadIdx.x;      // 0..8191
    const int l = t & 63, nt = (t >> 6) & 7, kt = (t >> 9) & 7, mlp = t >> 12;
    const int col = l & 15, quad = l >> 4;
    const int n = nt * 16 + col;
    const float* w1 = mlp ? cw1 : sw1;
    short frag[8];
    #pragma unroll
    for (int j = 0; j < 8; ++j) {
        int k = kt * 32 + quad * 8 + j;
        union { float f; unsigned u; } c; c.f = w1[k * HK_ + n];
        frag[j] = (short)((c.u + 0x7FFF + ((c.u >> 16) & 1)) >> 16);   // RNE
    }
    *(uint4*)(wtf + (size_t)t * 8) = *(const uint4*)frag;
    for (int s = t; s < NREP * B_ * ACC_STRIDE; s += 8192) ws_acc[s] = 0.f;
}

// ---------------------------------------------------------------------------
// Kernel 1 (FUSED): dual MLP via bf16 MFMA (16x16x32, 2-term A-split) PLUS the
// bucketed accumulation for this block's 32 rows.
//   Phase A: identical to the proven mlp_mfma kernel; sim goes to LDS (no
//            global round-trip), conf to global (needed by output kernel).
//   Phase B: 4 waves x 8 rows; exp(sim) from LDS; fire-and-forget LDS
//            atomicAdd (ds_add_f32, no RMW latency chain) into one shared
//            2688-float accumulator; then skip-zero global atomic flush into
//            one of NREP=4 per-batch replicas (16-way contention/address).
// ---------------------------------------------------------------------------
__launch_bounds__(256)
__global__ void mlp_accum_kernel(const float* __restrict__ fx, const short* __restrict__ wtf,
                                 const float* __restrict__ sb1, const float* __restrict__ sw2,
                                 const float* __restrict__ sb2, const float* __restrict__ cb1,
                                 const float* __restrict__ cw2, const float* __restrict__ cb2,
                                 const float* __restrict__ px, const int* __restrict__ questions,
                                 float* __restrict__ conf, float* __restrict__ ws_acc)
{
    __shared__ float accs[ACC_STRIDE];
    __shared__ float sim_l[32];

    const int tid  = threadIdx.x;
    for (int s = tid; s < ACC_STRIDE; s += 256) accs[s] = 0.f;   // used only after the barrier below

    const int w    = tid >> 6, l = tid & 63;
    const int col  = l & 15, quad = l >> 4;
    const int mlp  = w >> 1, mt = w & 1;
    const int row  = blockIdx.x * 32 + mt * 16 + col;  // A-operand m = lane&15

    f32x4 acc[8];
    #pragma unroll
    for (int nt = 0; nt < 8; ++nt) acc[nt] = (f32x4){0.f, 0.f, 0.f, 0.f};

    const float* fxrow = fx + (size_t)row * H_;
    const short* wf = wtf + (size_t)mlp * 32768 + (size_t)l * 8;

    #pragma unroll
    for (int kt = 0; kt < 8; ++kt) {
        float4 a0 = *(const float4*)(fxrow + kt * 32 + quad * 8);
        float4 a1 = *(const float4*)(fxrow + kt * 32 + quad * 8 + 4);
        float af[8] = {a0.x, a0.y, a0.z, a0.w, a1.x, a1.y, a1.z, a1.w};
        bf16x8 ahi, alo;
        #pragma unroll
        for (int i = 0; i < 8; ++i) {
            union { float f; unsigned u; } c; c.f = af[i];
            unsigned hi = c.u >> 16;                       // truncate: lo holds residual
            ahi[i] = (short)hi;
            union { float f; unsigned u; } h2; h2.u = hi << 16;
            union { float f; unsigned u; } c2; c2.f = af[i] - h2.f;
            alo[i] = (short)(c2.u >> 16);
        }
        const short* base = wf + (size_t)kt * 4096;
        #pragma unroll
        for (int nt = 0; nt < 8; ++nt) {
            bf16x8 bf = *(const bf16x8*)(base + nt * 512);
            acc[nt] = __builtin_amdgcn_mfma_f32_16x16x32_bf16(ahi, bf, acc[nt], 0, 0, 0);
            acc[nt] = __builtin_amdgcn_mfma_f32_16x16x32_bf16(alo, bf, acc[nt], 0, 0, 0);
        }
    }

    // fp32 layer-2 epilogue
    const float* b1 = mlp ? cb1 : sb1;
    const float* w2 = mlp ? cw2 : sw2;
    const float  b2v = mlp ? cb2[0] : sb2[0];
    float p[4] = {0.f, 0.f, 0.f, 0.f};
    #pragma unroll
    for (int nt = 0; nt < 8; ++nt) {
        float b1c = b1[nt * 16 + col];
        float w2c = w2[nt * 16 + col];
        #pragma unroll
        for (int j = 0; j < 4; ++j)
            p[j] += fmaxf(acc[nt][j] + b1c, 0.f) * w2c;
    }
    #pragma unroll
    for (int off = 8; off >= 1; off >>= 1)
        #pragma unroll
        for (int j = 0; j < 4; ++j) p[j] += __shfl_down(p[j], off, 16);

    if (col == 0) {
        #pragma unroll
        for (int j = 0; j < 4; ++j) {
            int rloc = mt * 16 + quad * 4 + j;             // D row = quad*4+reg
            float v = p[j] + b2v;
            if (mlp == 0) sim_l[rloc] = v;                              // stays on-chip
            else          conf[blockIdx.x * 32 + rloc] = 1.0f / (1.0f + expf(-v));
        }
    }
    __syncthreads();   // accs zeroed + sim_l written

    // Phase B: bucketed sums for this block's 32 rows. Wave g owns rows g+4t.
    const int row0 = blockIdx.x * 32;
    float Treg = 0.f;
    #pragma unroll
    for (int t = 0; t < 8; ++t) {
        const int il = w + 4 * t;
        const int i  = row0 + il;
        const int qi = questions[i];                  // wave-uniform -> scalar broadcast
        const float e = expf(sim_l[il]);
        const float v = px[(size_t)i * P_ + l];       // coalesced 256B per wave
        Treg += v;
        atomicAdd(&accs[qi * 64 + l], v);             // ds_add_f32, fire-and-forget
        atomicAdd(&accs[(20 + qi) * 64 + l], e * v);
        if (l == 0) {
            atomicAdd(&accs[2624 + qi], e);           // W_q (denominator exp-sum)
            atomicAdd(&accs[2644 + qi], 1.0f);        // n_q (group size)
        }
    }
    atomicAdd(&accs[2560 + l], Treg);                 // T
    __syncthreads();

    // skip-zero flush: adding 0.0 is a no-op, so skipping is always correct
    const int b   = blockIdx.x >> 6;                  // 64 blocks per batch
    const int rep = blockIdx.x & (NREP - 1);
    float* dst = ws_acc + (size_t)(b * NREP + rep) * ACC_STRIDE;
    for (int s = tid; s < ACC_STRIDE; s += 256) {
        const float vv = accs[s];
        if (vv != 0.f) atomicAdd(dst + s, vv);
    }
}

// ---------------------------------------------------------------------------
// Kernel 2: out = c*px + (1-c) * ((T - G_q + E_q) / denom_q), float4 per thread.
// Sums the NREP accumulator replicas (344 KB total, L2-hot).
// denom_q = (S - n_q) + W_q.
// ---------------------------------------------------------------------------
__global__ void output_kernel(const float* __restrict__ px, const float* __restrict__ conf,
                              const int* __restrict__ questions, const float* __restrict__ ws_acc,
                              float* __restrict__ out)
{
    const int idx = blockIdx.x * 256 + threadIdx.x;  // float4 units, 262144 total
    const int row = idx >> 4;                        // b*S + s
    const int p4  = idx & 15;
    const int b   = row >> 11;                       // S = 2048
    const float c = conf[row];
    const int   q = questions[row];

    float Tx=0.f,Ty=0.f,Tz=0.f,Tw=0.f;
    float Gx=0.f,Gy=0.f,Gz=0.f,Gw=0.f;
    float Ex=0.f,Ey=0.f,Ez=0.f,Ew=0.f;
    float Wq=0.f, nq=0.f;
    #pragma unroll
    for (int rep = 0; rep < NREP; ++rep) {
        const float* a = ws_acc + (size_t)(b * NREP + rep) * ACC_STRIDE;
        const float4 t4 = *(const float4*)(a + 2560 + p4 * 4);
        const float4 g4 = *(const float4*)(a + q * 64 + p4 * 4);
        const float4 e4 = *(const float4*)(a + (20 + q) * 64 + p4 * 4);
        Tx += t4.x; Ty += t4.y; Tz += t4.z; Tw += t4.w;
        Gx += g4.x; Gy += g4.y; Gz += g4.z; Gw += g4.w;
        Ex += e4.x; Ey += e4.y; Ez += e4.z; Ew += e4.w;
        Wq += a[2624 + q]; nq += a[2644 + q];
    }
    const float denom = ((float)S_ - nq) + Wq;
    const float inv = 1.0f / denom;
    const float4 pv = ((const float4*)px)[idx];
    const float om = 1.0f - c;
    float4 o;
    o.x = c * pv.x + om * ((Tx - Gx + Ex) * inv);
    o.y = c * pv.y + om * ((Ty - Gy + Ey) * inv);
    o.z = c * pv.z + om * ((Tz - Gz + Ez) * inv);
    o.w = c * pv.w + om * ((Tw - Gw + Ew) * inv);
    ((float4*)out)[idx] = o;
}

// ---------------------------------------------------------------------------
extern "C" void kernel_launch(void* const* d_in, const int* in_sizes, int n_in,
                              void* d_out, int out_size, void* d_ws, size_t ws_size,
                              hipStream_t stream) {
    const float* fx  = (const float*)d_in[0];
    const float* px  = (const float*)d_in[1];
    const float* sw1 = (const float*)d_in[2];
    const float* sb1 = (const float*)d_in[3];
    const float* sw2 = (const float*)d_in[4];
    const float* sb2 = (const float*)d_in[5];
    const float* cw1 = (const float*)d_in[6];
    const float* cb1 = (const float*)d_in[7];
    const float* cw2 = (const float*)d_in[8];
    const float* cb2 = (const float*)d_in[9];
    const int* questions = (const int*)d_in[10];
    float* out = (float*)d_out;

    float* ws     = (float*)d_ws;
    float* conf   = ws + WS_CONF;
    float* ws_acc = ws + WS_ACC;
    short* wtf    = (short*)(ws + WS_WT);

    prep_kernel<<<32, 256, 0, stream>>>(sw1, cw1, wtf, ws_acc);
    mlp_accum_kernel<<<M_ / 32, 256, 0, stream>>>(fx, wtf, sb1, sw2, sb2,
                                                  cb1, cw2, cb2, px, questions,
                                                  conf, ws_acc);
    output_kernel<<<(M_ * P_ / 4) / 256, 256, 0, stream>>>(px, conf, questions,
                                                           ws_acc, out);
}